// Round 6
// baseline (1499.246 us; speedup 1.0000x reference)
//
#include <hip/hip_runtime.h>
#include <math.h>

#define B_  4
#define S_  2048
#define D_  576
#define H_  9
#define HD_ 64
#define FF_ 1536
#define E_  8
#define TOK (B_*S_)   // 8192

typedef unsigned int   u32x4  __attribute__((ext_vector_type(4)));
typedef unsigned short u16x8  __attribute__((ext_vector_type(8)));
typedef __bf16         bf16x8 __attribute__((ext_vector_type(8)));
typedef _Float16       f16x8  __attribute__((ext_vector_type(8)));
typedef float          f32x4  __attribute__((ext_vector_type(4)));

__device__ __forceinline__ float b2f(unsigned short u) {
    union { unsigned int i; float f; } v; v.i = ((unsigned int)u) << 16; return v.f;
}
__device__ __forceinline__ unsigned short f2b(float f) {
    unsigned int u = __builtin_bit_cast(unsigned int, f);
    unsigned int r = 0x7fffu + ((u >> 16) & 1u);
    return (unsigned short)((u + r) >> 16);
}

// ---------------------------------------------------------------------------
// RMSNorm fp32 -> bf16 (for the expert phase)
// ---------------------------------------------------------------------------
__global__ __launch_bounds__(256)
void rmsnorm_k(const float* __restrict__ x, unsigned short* __restrict__ xn) {
    int tok = blockIdx.x, tid = threadIdx.x;
    const float* xr = x + (size_t)tok * D_;
    float v0 = xr[tid];
    float v1 = xr[tid + 256];
    float v2 = (tid < D_ - 512) ? xr[tid + 512] : 0.f;
    float ss = v0*v0 + v1*v1 + v2*v2;
    #pragma unroll
    for (int d = 1; d < 64; d <<= 1) ss += __shfl_xor(ss, d, 64);
    __shared__ float red[4];
    if ((tid & 63) == 0) red[tid >> 6] = ss;
    __syncthreads();
    float tot = red[0] + red[1] + red[2] + red[3];
    float rms = rsqrtf(tot / (float)D_ + 1e-6f);
    unsigned short* orow = xn + (size_t)tok * D_;
    orow[tid]       = f2b(v0 * rms);
    orow[tid + 256] = f2b(v1 * rms);
    if (tid < D_ - 512) orow[tid + 512] = f2b(v2 * rms);
}

// RMSNorm fp32 -> fp32, chunk-local output (for the high-precision q/kv path)
__global__ __launch_bounds__(256)
void rms32_k(const float* __restrict__ x, float* __restrict__ xn) {
    int tok = blockIdx.x, tid = threadIdx.x;
    const float* xr = x + (size_t)tok * D_;
    float v0 = xr[tid];
    float v1 = xr[tid + 256];
    float v2 = (tid < D_ - 512) ? xr[tid + 512] : 0.f;
    float ss = v0*v0 + v1*v1 + v2*v2;
    #pragma unroll
    for (int d = 1; d < 64; d <<= 1) ss += __shfl_xor(ss, d, 64);
    __shared__ float red[4];
    if ((tid & 63) == 0) red[tid >> 6] = ss;
    __syncthreads();
    float tot = red[0] + red[1] + red[2] + red[3];
    float rms = rsqrtf(tot / (float)D_ + 1e-6f);
    float* orow = xn + (size_t)tok * D_;
    orow[tid]       = v0 * rms;
    orow[tid + 256] = v1 * rms;
    if (tid < D_ - 512) orow[tid + 512] = v2 * rms;
}

// ---------------------------------------------------------------------------
// High-precision GEMM via scaled fp16 split: A = Ah + Al/2048, B = Bh + Bl/2048
// (Al, Bl stored pre-scaled by 2048 to stay fp16-normal). 3 MFMA passes:
// accH += Ah*Bh ; accL += Ah*Bl + Al*Bh ; C = accH + accL/2048.
// Effective rel error ~2^-22 — enough to keep MoE gating selection stable.
// A fp32 [M,K], B fp32 [K,N] (row stride ldb), C fp32.
// EPI: 0 = store fp32(acc); 1 = store fp32(acc + resid[idx])
// ---------------------------------------------------------------------------
template<int BN, int EPI>
__global__ __launch_bounds__(256)
void gemmS_k(const float* __restrict__ A, const float* __restrict__ Bm,
             float* __restrict__ Cout, const float* __restrict__ resid,
             int M, int N, int K, int ldb)
{
    constexpr int BM = 128, BK = 64, LDT = BK + 8;
    constexpr int WM = BM / 2, WN = BN / 2, MI = WM / 16, NJ = WN / 16;
    __shared__ alignas(16) _Float16 Ah[BM][LDT], Al[BM][LDT];
    __shared__ alignas(16) _Float16 Bh[BN][LDT], Bl[BN][LDT];
    const int tid  = threadIdx.x;
    const int bn0  = blockIdx.x * BN, bm0 = blockIdx.y * BM;
    const int lane = tid & 63, wave = tid >> 6;
    const int l    = lane & 15, quad = lane >> 4;
    const int wm   = wave >> 1, wn = wave & 1;

    f32x4 accH[MI][NJ], accL[MI][NJ];
    #pragma unroll
    for (int mi = 0; mi < MI; ++mi)
        #pragma unroll
        for (int nj = 0; nj < NJ; ++nj) {
            accH[mi][nj] = (f32x4){0.f, 0.f, 0.f, 0.f};
            accL[mi][nj] = (f32x4){0.f, 0.f, 0.f, 0.f};
        }

    const int nK = K / BK;
    for (int kc = 0; kc < nK; ++kc) {
        __syncthreads();
        // stage A: split fp32 -> (Ah, Al*2048)
        #pragma unroll
        for (int i = 0; i < (BM * BK) / 2048; ++i) {
            int u = i * 256 + tid;
            int r = u >> 3, c8 = (u & 7) * 8;
            const float* ga = A + (size_t)(bm0 + r) * K + kc * BK + c8;
            f16x8 hh, ll;
            #pragma unroll
            for (int j = 0; j < 8; ++j) {
                float v = ga[j];
                _Float16 h = (_Float16)v;
                hh[j] = h;
                ll[j] = (_Float16)((v - (float)h) * 2048.0f);
            }
            *(f16x8*)&Ah[r][c8] = hh;
            *(f16x8*)&Al[r][c8] = ll;
        }
        // stage B transposed: split fp32 -> (Bh, Bl*2048)
        #pragma unroll
        for (int i = 0; i < (BN * BK) / 2048; ++i) {
            int u = i * 256 + tid;
            int n = u % BN, k8 = (u / BN) * 8;
            const float* gB = Bm + (size_t)(kc * BK + k8) * ldb + bn0 + n;
            f16x8 hh, ll;
            #pragma unroll
            for (int j = 0; j < 8; ++j) {
                float v = gB[(size_t)j * ldb];
                _Float16 h = (_Float16)v;
                hh[j] = h;
                ll[j] = (_Float16)((v - (float)h) * 2048.0f);
            }
            *(f16x8*)&Bh[n][k8] = hh;
            *(f16x8*)&Bl[n][k8] = ll;
        }
        __syncthreads();
        #pragma unroll
        for (int ks = 0; ks < BK; ks += 32) {
            f16x8 ah[MI], al[MI], bh[NJ], bl[NJ];
            #pragma unroll
            for (int mi = 0; mi < MI; ++mi) {
                ah[mi] = *(const f16x8*)&Ah[wm * WM + mi * 16 + l][ks + quad * 8];
                al[mi] = *(const f16x8*)&Al[wm * WM + mi * 16 + l][ks + quad * 8];
            }
            #pragma unroll
            for (int nj = 0; nj < NJ; ++nj) {
                bh[nj] = *(const f16x8*)&Bh[wn * WN + nj * 16 + l][ks + quad * 8];
                bl[nj] = *(const f16x8*)&Bl[wn * WN + nj * 16 + l][ks + quad * 8];
            }
            #pragma unroll
            for (int mi = 0; mi < MI; ++mi)
                #pragma unroll
                for (int nj = 0; nj < NJ; ++nj) {
                    accH[mi][nj] = __builtin_amdgcn_mfma_f32_16x16x32_f16(
                        ah[mi], bh[nj], accH[mi][nj], 0, 0, 0);
                    accL[mi][nj] = __builtin_amdgcn_mfma_f32_16x16x32_f16(
                        ah[mi], bl[nj], accL[mi][nj], 0, 0, 0);
                    accL[mi][nj] = __builtin_amdgcn_mfma_f32_16x16x32_f16(
                        al[mi], bh[nj], accL[mi][nj], 0, 0, 0);
                }
        }
    }
    #pragma unroll
    for (int mi = 0; mi < MI; ++mi)
        #pragma unroll
        for (int nj = 0; nj < NJ; ++nj)
            #pragma unroll
            for (int r = 0; r < 4; ++r) {
                int row = bm0 + wm * WM + mi * 16 + quad * 4 + r;
                int col = bn0 + wn * WN + nj * 16 + l;
                float v = accH[mi][nj][r] + accL[mi][nj][r] * (1.0f / 2048.0f);
                size_t idx = (size_t)row * N + col;
                if constexpr (EPI == 0) Cout[idx] = v;
                else                    Cout[idx] = v + resid[idx];
            }
}

// ---------------------------------------------------------------------------
// Expert-phase MFMA GEMM: A bf16 internal, B fp32 weights (-> bf16 at staging).
// EPI: 0 = store bf16(acc)
//      3 = store bf16(gelu(bf16 resid[idx]) * acc)    (w3 fused gelu-mul)
//      4 = fp32 Cout[idx] += scale[row]*acc (RMW)     (w2 -> d_out fp32 acc)
// ---------------------------------------------------------------------------
template<int BN, int EPI>
__global__ __launch_bounds__(256)
void gemm_k(const unsigned short* __restrict__ A,
            const float* __restrict__ Bm,
            void* __restrict__ Cout,
            const void* __restrict__ resid,
            const float* __restrict__ scale, int scale_stride,
            int M, int N, int K, int ldb)
{
    constexpr int BM = 128, BK = 64, LDT = BK + 8;
    constexpr int WM = BM / 2, WN = BN / 2, MI = WM / 16, NJ = WN / 16;
    __shared__ alignas(16) unsigned short As[BM][LDT];
    __shared__ alignas(16) unsigned short Bs[BN][LDT];
    const int tid  = threadIdx.x;
    const int bn0  = blockIdx.x * BN, bm0 = blockIdx.y * BM;
    const int lane = tid & 63, wave = tid >> 6;
    const int l    = lane & 15, quad = lane >> 4;
    const int wm   = wave >> 1, wn = wave & 1;

    f32x4 acc[MI][NJ];
    #pragma unroll
    for (int mi = 0; mi < MI; ++mi)
        #pragma unroll
        for (int nj = 0; nj < NJ; ++nj) acc[mi][nj] = (f32x4){0.f, 0.f, 0.f, 0.f};

    const int nK = K / BK;
    for (int kc = 0; kc < nK; ++kc) {
        __syncthreads();
        #pragma unroll
        for (int i = 0; i < (BM * BK) / 2048; ++i) {
            int u = i * 256 + tid;
            int r = u >> 3, c8 = (u & 7) * 8;
            *(u32x4*)&As[r][c8] =
                *(const u32x4*)(A + (size_t)(bm0 + r) * K + kc * BK + c8);
        }
        #pragma unroll
        for (int i = 0; i < (BN * BK) / 2048; ++i) {
            int u = i * 256 + tid;
            int n = u % BN, k8 = (u / BN) * 8;
            const float* gB = Bm + (size_t)(kc * BK + k8) * ldb + bn0 + n;
            u16x8 tmp;
            #pragma unroll
            for (int j = 0; j < 8; ++j) tmp[j] = f2b(gB[(size_t)j * ldb]);
            *(u16x8*)&Bs[n][k8] = tmp;
        }
        __syncthreads();
        #pragma unroll
        for (int ks = 0; ks < BK; ks += 32) {
            bf16x8 af[MI], bfr[NJ];
            #pragma unroll
            for (int mi = 0; mi < MI; ++mi)
                af[mi] = __builtin_bit_cast(bf16x8,
                    *(const u32x4*)&As[wm * WM + mi * 16 + l][ks + quad * 8]);
            #pragma unroll
            for (int nj = 0; nj < NJ; ++nj)
                bfr[nj] = __builtin_bit_cast(bf16x8,
                    *(const u32x4*)&Bs[wn * WN + nj * 16 + l][ks + quad * 8]);
            #pragma unroll
            for (int mi = 0; mi < MI; ++mi)
                #pragma unroll
                for (int nj = 0; nj < NJ; ++nj)
                    acc[mi][nj] = __builtin_amdgcn_mfma_f32_16x16x32_bf16(
                        af[mi], bfr[nj], acc[mi][nj], 0, 0, 0);
        }
    }
    #pragma unroll
    for (int mi = 0; mi < MI; ++mi)
        #pragma unroll
        for (int nj = 0; nj < NJ; ++nj)
            #pragma unroll
            for (int r = 0; r < 4; ++r) {
                int row = bm0 + wm * WM + mi * 16 + quad * 4 + r;
                int col = bn0 + wn * WN + nj * 16 + l;
                float v = acc[mi][nj][r];
                size_t idx = (size_t)row * N + col;
                if constexpr (EPI == 0) {
                    ((unsigned short*)Cout)[idx] = f2b(v);
                } else if constexpr (EPI == 3) {
                    float hv = b2f(((const unsigned short*)resid)[idx]);
                    float g = 0.5f * hv * (1.0f + erff(hv * 0.70710678118654752f));
                    ((unsigned short*)Cout)[idx] = f2b(g * v);
                } else {
                    float sc = scale ? scale[(size_t)row * scale_stride] : 1.0f;
                    ((float*)Cout)[idx] += sc * v;
                }
            }
}

// ---------------------------------------------------------------------------
// Per-position cross-head attention, full fp32. One wave per position; lane =
// d in [0,64). RoPE fused on q load. q/kv are LOCAL chunk rows (fp32).
// Output fp32 in (b,h,s,d) flattened order.
// ---------------------------------------------------------------------------
__global__ __launch_bounds__(256)
void attn32_k(const float* __restrict__ q,   // [ct][H][64]
              const float* __restrict__ kv,  // [ct][H][128]
              float* __restrict__ ao,        // [(b*H+h)*S+s][64]
              int pos0)
{
    int pl   = blockIdx.x * 4 + (threadIdx.x >> 6);
    int lane = threadIdx.x & 63;
    int pos  = pos0 + pl;
    int b = pos >> 11, s = pos & 2047;

    const float* qp  = q  + (size_t)pl * 576;
    const float* kvp = kv + (size_t)pl * 1152;

    int i = lane >> 1;
    float theta = powf(10000.f, -(float)i * (1.0f / 32.0f));
    float sn, cs;
    sincosf((float)s * theta, &sn, &cs);

    float qr[H_], kr[H_], vr[H_];
    #pragma unroll
    for (int h = 0; h < H_; ++h) {
        float qv = qp[h * 64 + lane];
        float qo = __shfl_xor(qv, 1, 64);
        qr[h] = (lane & 1) ? (qo * sn + qv * cs) : (qv * cs - qo * sn);
        kr[h] = kvp[h * 128 + lane];
        vr[h] = kvp[h * 128 + 64 + lane];
    }

    #pragma unroll
    for (int h = 0; h < H_; ++h) {
        float sc[H_];
        #pragma unroll
        for (int t = 0; t < H_; ++t) {
            float p = qr[h] * kr[t];
            #pragma unroll
            for (int d = 1; d < 64; d <<= 1) p += __shfl_xor(p, d, 64);
            sc[t] = p * 0.125f;
        }
        float mx = sc[0];
        #pragma unroll
        for (int t = 1; t < H_; ++t) mx = fmaxf(mx, sc[t]);
        float ssum = 0.f;
        #pragma unroll
        for (int t = 0; t < H_; ++t) { sc[t] = __expf(sc[t] - mx); ssum += sc[t]; }
        float inv = 1.0f / ssum;
        float ov = 0.f;
        #pragma unroll
        for (int t = 0; t < H_; ++t) ov += sc[t] * vr[t];
        ao[((size_t)(b * H_ + h) * S_ + s) * 64 + lane] = ov * inv;
    }
}

// ---------------------------------------------------------------------------
// Gating from fp32 x2 (pre-norm): logits = (x2 @ gate_w) * rms(x2) — exact
// fp32. softmax, top-2 renorm. One wave (64 thr) per token.
// ---------------------------------------------------------------------------
__global__ __launch_bounds__(64)
void gate_k(const float* __restrict__ x2,
            const float* __restrict__ gw,
            float* __restrict__ comb)
{
    int tok = blockIdx.x, lane = threadIdx.x;
    float acc[8];
    #pragma unroll
    for (int e = 0; e < 8; ++e) acc[e] = 0.f;
    float ss = 0.f;
    for (int d = lane; d < D_; d += 64) {
        float xv = x2[(size_t)tok * D_ + d];
        ss += xv * xv;
        const float* wr = gw + (size_t)d * 8;
        #pragma unroll
        for (int e = 0; e < 8; ++e) acc[e] += xv * wr[e];
    }
    #pragma unroll
    for (int d = 1; d < 64; d <<= 1) ss += __shfl_xor(ss, d, 64);
    #pragma unroll
    for (int e = 0; e < 8; ++e)
        #pragma unroll
        for (int d = 1; d < 64; d <<= 1) acc[e] += __shfl_xor(acc[e], d, 64);
    if (lane == 0) {
        float rms = rsqrtf(ss / (float)D_ + 1e-6f);
        #pragma unroll
        for (int e = 0; e < 8; ++e) acc[e] *= rms;
        float mx = acc[0];
        #pragma unroll
        for (int e = 1; e < 8; ++e) mx = fmaxf(mx, acc[e]);
        float g[8], ssum = 0.f;
        #pragma unroll
        for (int e = 0; e < 8; ++e) { g[e] = __expf(acc[e] - mx); ssum += g[e]; }
        #pragma unroll
        for (int e = 0; e < 8; ++e) g[e] /= ssum;
        int i1 = 0;
        #pragma unroll
        for (int e = 1; e < 8; ++e) if (g[e] > g[i1]) i1 = e;
        int i2 = -1;
        #pragma unroll
        for (int e = 0; e < 8; ++e)
            if (e != i1 && (i2 < 0 || g[e] > g[i2])) i2 = e;
        float s2 = g[i1] + g[i2];
        float outw[8];
        #pragma unroll
        for (int e = 0; e < 8; ++e) outw[e] = 0.f;
        outw[i1] = g[i1] / s2;
        outw[i2] = g[i2] / s2;
        #pragma unroll
        for (int e = 0; e < 8; ++e) comb[(size_t)tok * 8 + e] = outw[e];
    }
}

// ---------------------------------------------------------------------------
extern "C" void kernel_launch(void* const* d_in, const int* in_sizes, int n_in,
                              void* d_out, int out_size, void* d_ws, size_t ws_size,
                              hipStream_t stream)
{
    const float* x      = (const float*)d_in[0];
    const float* q_w    = (const float*)d_in[1];
    const float* kv_w   = (const float*)d_in[2];
    const float* o_w    = (const float*)d_in[3];
    const float* gate_w = (const float*)d_in[4];
    const float* w1     = (const float*)d_in[5];
    const float* w2     = (const float*)d_in[6];
    const float* w3     = (const float*)d_in[7];
    const float* sw1    = (const float*)d_in[8];
    const float* sw2    = (const float*)d_in[9];
    const float* sw3    = (const float*)d_in[10];
    float* out = (float*)d_out;   // fp32: holds x2, then accumulates experts

    const size_t XN     = (size_t)TOK * D_ * 2;   //  9,437,184 (bf16 TOK x D)
    const size_t COMBSZ = (size_t)TOK * 8 * 4;
    const size_t T1FULL = (size_t)TOK * FF_ * 2;  // 25,165,824
    char* ws = (char*)d_ws;
    unsigned short* xn16 = (unsigned short*)ws;          // [0, XN)      persists
    float*          ao32 = (float*)(ws + XN);            // [XN, 3XN)    phase A
    float*          comb = (float*)(ws + XN);            // phase B (ao32 dead)

    // phase-A chunking: footprint = 3XN + 8XN/TC  (xn32c 2XN/TC + qc 2XN/TC + kvc 4XN/TC)
    int TC = 64;
    if      (3*XN + 8*XN    <= ws_size) TC = 1;
    else if (3*XN + 8*XN/2  <= ws_size) TC = 2;
    else if (3*XN + 8*XN/4  <= ws_size) TC = 4;
    else if (3*XN + 8*XN/8  <= ws_size) TC = 8;
    else if (3*XN + 8*XN/16 <= ws_size) TC = 16;
    else if (3*XN + 8*XN/32 <= ws_size) TC = 32;
    const int CT = TOK / TC;
    float* xn32c = (float*)(ws + 3*XN);
    float* qc    = xn32c + (size_t)CT * D_;
    float* kvc   = qc    + (size_t)CT * D_;

    // expert-phase FF chunking: XN + COMBSZ + T1FULL/FC <= ws_size
    int FC = 8;
    if      (XN + COMBSZ + T1FULL   <= ws_size) FC = 1;
    else if (XN + COMBSZ + T1FULL/2 <= ws_size) FC = 2;
    else if (XN + COMBSZ + T1FULL/4 <= ws_size) FC = 4;
    unsigned short* t1 = (unsigned short*)(ws + XN + COMBSZ);
    const int FFc = FF_ / FC;

    // 1) xn16 = rmsnorm(x) (bf16, for experts later — recomputed cheaply here)
    //    phase A per chunk: xn32c (fp32), q, kv (split GEMM), attention
    for (int t = 0; t < TC; ++t) {
        const float* xc = x + (size_t)t * CT * D_;
        rms32_k<<<CT, 256, 0, stream>>>(xc, xn32c);
        gemmS_k<64, 0><<<dim3(D_ / 64, CT / 128), 256, 0, stream>>>(
            xn32c, q_w, qc, nullptr, CT, D_, D_, D_);
        gemmS_k<64, 0><<<dim3(1152 / 64, CT / 128), 256, 0, stream>>>(
            xn32c, kv_w, kvc, nullptr, CT, 1152, D_, 1152);
        attn32_k<<<CT / 4, 256, 0, stream>>>(qc, kvc, ao32, t * CT);
    }
    // 2) x2 = ao @ o_w + x  -> d_out (fp32, split GEMM)
    gemmS_k<64, 1><<<dim3(D_ / 64, TOK / 128), 256, 0, stream>>>(
        ao32, o_w, out, x, TOK, D_, D_, D_);
    // 3) xn16 = rmsnorm(x2) (bf16, expert input)
    rmsnorm_k<<<TOK, 256, 0, stream>>>(out, xn16);
    // 4) gating (exact fp32 from pre-norm x2)
    gate_k<<<TOK, 64, 0, stream>>>(out, gate_w, comb);
    // 5) experts (e == E_ is the shared expert, scale 1); fp32 RMW into out
    for (int e = 0; e <= E_; ++e) {
        const float* w1e = (e < E_) ? w1 + (size_t)e * D_ * FF_ : sw1;
        const float* w3e = (e < E_) ? w3 + (size_t)e * D_ * FF_ : sw3;
        const float* w2e = (e < E_) ? w2 + (size_t)e * FF_ * D_ : sw2;
        const float* sc  = (e < E_) ? comb + e : nullptr;
        for (int c = 0; c < FC; ++c) {
            const float* w1c = w1e + (size_t)c * FFc;
            const float* w3c = w3e + (size_t)c * FFc;
            const float* w2c = w2e + (size_t)c * FFc * D_;
            if (FFc % 128 == 0) {
                gemm_k<128, 0><<<dim3(FFc / 128, TOK / 128), 256, 0, stream>>>(
                    xn16, w1c, t1, nullptr, nullptr, 0, TOK, FFc, D_, FF_);
                gemm_k<128, 3><<<dim3(FFc / 128, TOK / 128), 256, 0, stream>>>(
                    xn16, w3c, t1, t1, nullptr, 0, TOK, FFc, D_, FF_);
            } else {
                gemm_k<64, 0><<<dim3(FFc / 64, TOK / 128), 256, 0, stream>>>(
                    xn16, w1c, t1, nullptr, nullptr, 0, TOK, FFc, D_, FF_);
                gemm_k<64, 3><<<dim3(FFc / 64, TOK / 128), 256, 0, stream>>>(
                    xn16, w3c, t1, t1, nullptr, 0, TOK, FFc, D_, FF_);
            }
            gemm_k<64, 4><<<dim3(D_ / 64, TOK / 128), 256, 0, stream>>>(
                t1, w2c, out, nullptr, sc, 8, TOK, D_, FFc, D_);
        }
    }
}